// Round 16
// baseline (482.401 us; speedup 1.0000x reference)
//
#include <hip/hip_runtime.h>

#define NN 50000
#define NE 800000
#define BINS 98      // bins of 512 nodes per branch
#define CAP 12288    // per-bin capacity (u32 records / ushort csr entries)
#define EPB 4096     // edges per phase-1 block
#define P1B ((NE + EPB - 1) / EPB)  // 196 blocks per branch
#define BINB (3 * P1B)              // 588 bin blocks
#define WB ((NN + 3) / 4)           // 12500

typedef __attribute__((ext_vector_type(8))) short short8;
typedef __attribute__((ext_vector_type(4))) float f32x4;
typedef __attribute__((ext_vector_type(8))) unsigned short ushort8v;
typedef __attribute__((ext_vector_type(4))) unsigned short ushort4v;
typedef _Float16 half8 __attribute__((ext_vector_type(8)));

__device__ __forceinline__ ushort f2h(float f) {
    _Float16 h = (_Float16)f;
    return __builtin_bit_cast(ushort, h);
}
__device__ __forceinline__ float h2f(ushort u) {
    return (float)__builtin_bit_cast(_Float16, u);
}

__device__ __forceinline__ int wave_incl_scan(int v, int lane) {
#pragma unroll
    for (int d = 1; d < 64; d <<= 1) {
        int u = __shfl_up(v, d);
        if (lane >= d) v += u;
    }
    return v;
}

// ---------------- setup dispatch: {edge binning | conv x16 | conv W1 | conv W2} ----

__global__ __launch_bounds__(256) void k_setup(
    const int* __restrict__ e0, const int* __restrict__ e1,
    const int* __restrict__ e2, int* __restrict__ g_cur,
    unsigned* __restrict__ g_bins,
    const float* __restrict__ x, ushort* __restrict__ x16,
    const float* __restrict__ w1a, const float* __restrict__ w1b,
    const float* __restrict__ w1c, ushort* __restrict__ BT1all,
    const float* __restrict__ w2a, const float* __restrict__ w2b,
    const float* __restrict__ w2c, ushort* __restrict__ BT2all) {
    const int tid = threadIdx.x;

    if (blockIdx.x < BINB) {
        const int br = blockIdx.x / P1B;
        const int cb = blockIdx.x % P1B;
        const int* ep = (br == 0 ? e0 : br == 1 ? e1 : e2);
        const int e_base = cb * EPB;

        __shared__ int s_cnt[BINS];
        __shared__ int s_start[BINS];
        __shared__ int s_cur[BINS];
        __shared__ int s_gb[BINS];
        __shared__ unsigned s_stage[EPB];

        if (tid < BINS) s_cnt[tid] = 0;
        __syncthreads();

        int4 s4[4], d4[4];
        bool valid[4];
#pragma unroll
        for (int i = 0; i < 4; ++i) {
            int idx = e_base + i * 1024 + tid * 4;
            valid[i] = (idx < NE);
            if (valid[i]) {
                s4[i] = *(const int4*)&ep[idx];
                d4[i] = *(const int4*)&ep[NE + idx];
                atomicAdd(&s_cnt[d4[i].x >> 9], 1);
                atomicAdd(&s_cnt[d4[i].y >> 9], 1);
                atomicAdd(&s_cnt[d4[i].z >> 9], 1);
                atomicAdd(&s_cnt[d4[i].w >> 9], 1);
            }
        }
        __syncthreads();
        if (tid == 0) {
            int run = 0;
            for (int b = 0; b < BINS; ++b) {
                s_start[b] = run;
                run += s_cnt[b];
            }
        }
        __syncthreads();
        if (tid < BINS) {
            s_cur[tid] = s_start[tid];
            int c = s_cnt[tid];
            int pc = (c + 15) & ~15;
            s_gb[tid] = (c > 0) ? atomicAdd(&g_cur[br * BINS + tid], pc) : 0;
        }
        __syncthreads();

#pragma unroll
        for (int i = 0; i < 4; ++i) {
            if (valid[i]) {
                int ss[4] = {s4[i].x, s4[i].y, s4[i].z, s4[i].w};
                int dd[4] = {d4[i].x, d4[i].y, d4[i].z, d4[i].w};
#pragma unroll
                for (int q = 0; q < 4; ++q) {
                    int bin = dd[q] >> 9;
                    int pos = atomicAdd(&s_cur[bin], 1);
                    s_stage[pos] = ((unsigned)(dd[q] & 511) << 16) | (unsigned)ss[q];
                }
            }
        }
        __syncthreads();

        for (int b = 0; b < BINS; ++b) {
            int c = s_cnt[b];
            if (c == 0) continue;
            int st = s_start[b];
            int gb = s_gb[b];
            int pc = (c + 15) & ~15;
            if (gb + pc > CAP) pc = (gb < CAP) ? (CAP - gb) : 0;
            size_t obase = (size_t)(br * BINS + b) * CAP + gb;
            for (int j = tid; j < pc; j += 256)
                g_bins[obase + j] = (j < c) ? s_stage[st + j] : 0x80000000u;
        }
        return;
    }

    int bb = blockIdx.x - BINB;
    if (bb < WB) {
        const int wid = tid >> 6, lane = tid & 63;
        const int row = bb * 4 + wid;
        if (row >= NN) return;
        float4 v = *(const float4*)&x[(size_t)row * 256 + lane * 4];
        ushort4 o;
        o.x = f2h(v.x); o.y = f2h(v.y); o.z = f2h(v.z); o.w = f2h(v.w);
        *(ushort4*)&x16[(size_t)row * 256 + lane * 4] = o;
        return;
    }
    bb -= WB;
    if (bb < 768) {
        int idx = bb * 256 + tid;  // 3 * 65536
        int b = idx >> 16, r = idx & 65535;
        int k = r >> 8, n = r & 255;
        const float* W = (b == 0 ? w1a : b == 1 ? w1b : w1c);
        BT1all[(size_t)b * 65536 + (size_t)n * 256 + k] = f2h(W[r]);
        return;
    }
    bb -= 768;
    {
        int idx = bb * 256 + tid;  // 3 * 32768
        int b = idx >> 15, r = idx & 32767;
        int k = r >> 7, n = r & 127;
        const float* W = (b == 0 ? w2a : b == 1 ? w2b : w2c);
        BT2all[(size_t)b * 32768 + (size_t)n * 256 + k] = f2h(W[r]);
    }
}

// ---------------- combined dispatch: {CSR build (294 blocks) | GEMM1 (1176)} ----

#define BGB 391  // gemm1 M-tiles per branch

__global__ __launch_bounds__(512) void k_build_gemm1(
    const unsigned* __restrict__ g_bins, const int* __restrict__ g_cur,
    ushort* __restrict__ g_csr, int* __restrict__ seg3, int* __restrict__ cnt3,
    float* __restrict__ dinv3,
    const ushort* __restrict__ x16, const ushort* __restrict__ BT1all,
    ushort* __restrict__ hs16all) {
    __shared__ ushort sA[2][128 * 32];
    __shared__ ushort sB[2][256 * 32];
    __shared__ int s_cnt[512];
    __shared__ int s_wsum[8];

    const int t = threadIdx.x, lane = t & 63, wid = t >> 6;

    if (blockIdx.x < 3 * BINS) {
        const int bid = blockIdx.x;
        const int br = bid / BINS;
        const int b2 = bid % BINS;
        const size_t base = (size_t)bid * CAP;
        const int node0 = b2 << 9;

        s_cnt[t] = 0;
        __syncthreads();

        const int total = min(g_cur[bid], CAP);
        for (int j = t; j < total; j += 512) {
            unsigned p = g_bins[base + j];
            if (!(p & 0x80000000u)) atomicAdd(&s_cnt[(p >> 16) & 0x1FF], 1);
        }
        __syncthreads();

        int c = s_cnt[t];
        int incl = wave_incl_scan(c, lane);
        if (lane == 63) s_wsum[wid] = incl;
        __syncthreads();
        int wpre = 0;
        for (int i = 0; i < wid; ++i) wpre += s_wsum[i];
        int ex = wpre + incl - c;

        int node = node0 + t;
        if (node < NN) {
            int g = br * NN + node;
            seg3[g] = (int)base + ex;
            cnt3[g] = c;
            dinv3[g] = rsqrtf((float)(c + 1));
        }
        __syncthreads();
        s_cnt[t] = ex;  // cursor
        __syncthreads();

        for (int j = t; j < total; j += 512) {
            unsigned p = g_bins[base + j];
            if (!(p & 0x80000000u)) {
                int loc = (p >> 16) & 0x1FF;
                int pos = atomicAdd(&s_cnt[loc], 1);
                g_csr[base + pos] = (ushort)(p & 0xFFFFu);
            }
        }
        return;
    }

    // ---------------- GEMM1 (512 threads, BM=128, BN=256, K=256) ----------
    constexpr int BM = 128, N = 256, KK = 256, BK = 32;
    constexpr int NW = 8, WGN = 4, NSTEP = KK / BK;
    const int sbid = blockIdx.x - 3 * BINS;
    int q = sbid >> 3, r = sbid & 7;
    int bid = (q / 3) * 8 + r;  // M-tile
    int kb = q % 3;             // branch
    if (bid >= BGB) return;

    const ushort* BT = BT1all + (size_t)kb * 65536;
    ushort* C = hs16all + (size_t)kb * NN * 256;
    const int wm = (wid / WGN) * 64, wn = (wid % WGN) * 64;
    const int bm = bid * BM;

    f32x4 zero = {0.f, 0.f, 0.f, 0.f};
    f32x4 acc[4][4];
#pragma unroll
    for (int m = 0; m < 4; ++m)
#pragma unroll
        for (int n = 0; n < 4; ++n) acc[m][n] = zero;

    auto stage = [&](int buf, int kt) {
        {
            int off = wid << 10;  // A: 1 issue
            int la = off + lane * 16;
            int row = la >> 6;
            int slot = (la >> 4) & 3;
            int scol = (slot ^ (row & 3)) << 4;
            int grow = bm + row;
            if (grow > NN - 1) grow = NN - 1;
            const char* ga = (const char*)x16 + (size_t)grow * (KK * 2) + kt * 2 + scol;
            __builtin_amdgcn_global_load_lds(
                (__attribute__((address_space(1))) const void*)ga,
                (__attribute__((address_space(3))) void*)((char*)sA[buf] + off), 16, 0, 0);
        }
#pragma unroll
        for (int i = 0; i < 2; ++i) {  // B: 2 issues
            int off = (wid + i * NW) << 10;
            int la = off + lane * 16;
            int row = la >> 6;
            int slot = (la >> 4) & 3;
            int scol = (slot ^ (row & 3)) << 4;
            const char* ga = (const char*)BT + (size_t)row * (KK * 2) + kt * 2 + scol;
            __builtin_amdgcn_global_load_lds(
                (__attribute__((address_space(1))) const void*)ga,
                (__attribute__((address_space(3))) void*)((char*)sB[buf] + off), 16, 0, 0);
        }
    };

    stage(0, 0);
    __syncthreads();

    int cur = 0;
    for (int ts = 0; ts < NSTEP; ++ts) {
        if (ts + 1 < NSTEP) stage(cur ^ 1, (ts + 1) * BK);

        const int s = lane >> 4;
        const int r0 = lane & 15;
        short8 af[4], bf[4];
#pragma unroll
        for (int m = 0; m < 4; ++m) {
            int row = wm + m * 16 + r0;
            af[m] = *(const short8*)((const char*)sA[cur] + row * 64 + ((s ^ (row & 3)) << 4));
        }
#pragma unroll
        for (int n = 0; n < 4; ++n) {
            int row = wn + n * 16 + r0;
            bf[n] = *(const short8*)((const char*)sB[cur] + row * 64 + ((s ^ (row & 3)) << 4));
        }
#pragma unroll
        for (int m = 0; m < 4; ++m)
#pragma unroll
            for (int n = 0; n < 4; ++n)
                acc[m][n] = __builtin_amdgcn_mfma_f32_16x16x32_f16(
                    __builtin_bit_cast(half8, af[m]), __builtin_bit_cast(half8, bf[n]),
                    acc[m][n], 0, 0, 0);
        __syncthreads();
        cur ^= 1;
    }

    const int cr0 = (lane >> 4) * 4;
    const int cc = lane & 15;
#pragma unroll
    for (int m = 0; m < 4; ++m) {
#pragma unroll
        for (int rg = 0; rg < 4; ++rg) {
            int row = bm + wm + m * 16 + cr0 + rg;
            if (row < NN) {
#pragma unroll
                for (int n = 0; n < 4; ++n)
                    C[(size_t)row * N + wn + n * 16 + cc] = f2h(acc[m][n][rg]);
            }
        }
    }
}

// ---------------- FUSED layer-1 aggregation + GEMM2 ----------------
// Block = 64 dest nodes of one branch, 256 threads (4 waves).
// Phase A: each wave gathers 16 nodes (per-wave work sigma/mu ~6% -> barrier
// straggle ~2%, fixing r11's 16-node-variance failure); h1 rows land in a
// 32KB XOR-swizzled LDS tile -- h1 never touches HBM (saves 75MB write +
// 77MB re-read + the gemm2 dispatch).
// Phase B: hs2[64][128] = dinv * (h1 @ W2), fp16 MFMA vs L2-hot W2^T.

__global__ __launch_bounds__(256) void k_agg1g2(
    const ushort* __restrict__ hs16all, const int* __restrict__ seg3,
    const int* __restrict__ cnt3, const ushort* __restrict__ g_csr,
    const float* __restrict__ dinv3,
    const float* __restrict__ b1a, const float* __restrict__ b1b,
    const float* __restrict__ b1c,
    const ushort* __restrict__ BT2all, ushort* __restrict__ hs2all) {
    constexpr int TPB = (NN + 63) / 64;  // 782 tiles per branch
    const int br = blockIdx.x / TPB;
    const int blk = blockIdx.x % TPB;
    const int node0 = blk * 64;
    const int t = threadIdx.x, lane = t & 63, wid = t >> 6;
    const int half = lane >> 5, l32 = lane & 31;

    __shared__ ushort h1s[64 * 256];  // 32 KB

    const ushort* hs = hs16all + (size_t)br * NN * 256;
    const float* dv = dinv3 + (size_t)br * NN;
    const float* bias = (br == 0 ? b1a : br == 1 ? b1b : b1c);
    const size_t colb = (size_t)l32 * 8;

    // Phase A: wave wid gathers rows wid*16 .. wid*16+15
#pragma unroll 1
    for (int q = 0; q < 16; ++q) {
        const int r = wid * 16 + q;
        const int node = node0 + r;
        if (node < NN) {
            const int g = br * NN + node;
            const ushort* csr = g_csr + seg3[g];
            const int len = cnt3[g] + 1;

            float acc[8] = {0.f, 0.f, 0.f, 0.f, 0.f, 0.f, 0.f, 0.f};
            int i = half;
            for (; i + 6 < len; i += 8) {
                int s0 = (i == 0) ? node : (int)csr[i - 1];
                int s1 = (int)csr[i + 1];
                int s2 = (int)csr[i + 3];
                int s3 = (int)csr[i + 5];
                float d0 = dv[s0], d1 = dv[s1], d2 = dv[s2], d3 = dv[s3];
                ushort8v v0 = *(const ushort8v*)&hs[(size_t)s0 * 256 + colb];
                ushort8v v1 = *(const ushort8v*)&hs[(size_t)s1 * 256 + colb];
                ushort8v v2 = *(const ushort8v*)&hs[(size_t)s2 * 256 + colb];
                ushort8v v3 = *(const ushort8v*)&hs[(size_t)s3 * 256 + colb];
#pragma unroll
                for (int j = 0; j < 8; ++j)
                    acc[j] += (d0 * h2f(v0[j]) + d1 * h2f(v1[j])) +
                              (d2 * h2f(v2[j]) + d3 * h2f(v3[j]));
            }
            for (; i < len; i += 2) {
                int s = (i == 0) ? node : (int)csr[i - 1];
                float d = dv[s];
                ushort8v v = *(const ushort8v*)&hs[(size_t)s * 256 + colb];
#pragma unroll
                for (int j = 0; j < 8; ++j) acc[j] += d * h2f(v[j]);
            }
#pragma unroll
            for (int j = 0; j < 8; ++j) acc[j] += __shfl_xor(acc[j], 32);

            if (half == 0) {
                const float di = dv[node];
                ushort8v o;
#pragma unroll
                for (int j = 0; j < 8; ++j) {
                    float rr = fmaxf(di * acc[j] + bias[l32 * 8 + j], 0.f);
                    o[j] = f2h(rr);
                }
                *(ushort8v*)((char*)h1s + r * 512 + ((l32 ^ (r & 7)) << 4)) = o;
            }
        } else if (half == 0) {
            ushort8v z = {0, 0, 0, 0, 0, 0, 0, 0};
            *(ushort8v*)((char*)h1s + r * 512 + ((l32 ^ (r & 7)) << 4)) = z;
        }
    }
    __syncthreads();

    // Phase B: GEMM2. Wave wid owns rows wid*16..+15, all 128 cols, K=256.
    const ushort* BT2 = BT2all + (size_t)br * 32768;
    const int r0 = lane & 15, s = lane >> 4;
    f32x4 zero = {0.f, 0.f, 0.f, 0.f};
    f32x4 acc2[8];
#pragma unroll
    for (int n = 0; n < 8; ++n) acc2[n] = zero;
    const int arow = wid * 16 + r0;
#pragma unroll
    for (int ks = 0; ks < 8; ++ks) {
        const int kt = ks * 32;
        const int slot = (ks * 4 + s) ^ (r0 & 7);
        short8 a = *(const short8*)((const char*)h1s + arow * 512 + (slot << 4));
#pragma unroll
        for (int n = 0; n < 8; ++n) {
            short8 bfr = *(const short8*)&BT2[(size_t)(n * 16 + r0) * 256 + kt + s * 8];
            acc2[n] = __builtin_amdgcn_mfma_f32_16x16x32_f16(
                __builtin_bit_cast(half8, a), __builtin_bit_cast(half8, bfr),
                acc2[n], 0, 0, 0);
        }
    }

    const int cc = lane & 15;
    const int cr0 = (lane >> 4) * 4;
#pragma unroll
    for (int rg = 0; rg < 4; ++rg) {
        const int node = node0 + wid * 16 + cr0 + rg;
        if (node < NN) {
            float dvv = dv[node];
            ushort* orow = hs2all + ((size_t)br * NN + node) * 128;
#pragma unroll
            for (int n = 0; n < 8; ++n)
                orow[n * 16 + cc] = f2h(acc2[n][rg] * dvv);
        }
    }
}

// ---------------- fused layer-2 aggregation (x3) + attention ----------------

__global__ __launch_bounds__(256) void k_final(const ushort* __restrict__ hs2all,
                                               const int* __restrict__ seg3,
                                               const int* __restrict__ cnt3,
                                               const ushort* __restrict__ g_csr,
                                               const float* __restrict__ dinv3,
                                               const float* __restrict__ b2a,
                                               const float* __restrict__ b2b,
                                               const float* __restrict__ b2c,
                                               const float* __restrict__ attn_w,
                                               const float* __restrict__ attn_b,
                                               float* __restrict__ out) {
    const int wid = threadIdx.x >> 6;
    const int lane = threadIdx.x & 63;
    const int node = blockIdx.x * 4 + wid;
    if (node >= NN) return;
    const int half = lane >> 5, l32 = lane & 31;
    const size_t colb = (size_t)l32 * 4;

    float f[3][4];
#pragma unroll
    for (int b = 0; b < 3; ++b) {
        const int g = b * NN + node;
        const ushort* hs = hs2all + (size_t)b * NN * 128;
        const ushort* csr = g_csr + seg3[g];
        const int len = cnt3[g] + 1;
        float acc[4] = {0.f, 0.f, 0.f, 0.f};
        int i = half;
        for (; i + 6 < len; i += 8) {
            int s0 = (i == 0) ? node : (int)csr[i - 1];
            int s1 = (int)csr[i + 1];
            int s2 = (int)csr[i + 3];
            int s3 = (int)csr[i + 5];
            ushort4v v0 = *(const ushort4v*)&hs[(size_t)s0 * 128 + colb];
            ushort4v v1 = *(const ushort4v*)&hs[(size_t)s1 * 128 + colb];
            ushort4v v2 = *(const ushort4v*)&hs[(size_t)s2 * 128 + colb];
            ushort4v v3 = *(const ushort4v*)&hs[(size_t)s3 * 128 + colb];
#pragma unroll
            for (int j = 0; j < 4; ++j)
                acc[j] += (h2f(v0[j]) + h2f(v1[j])) + (h2f(v2[j]) + h2f(v3[j]));
        }
        for (; i < len; i += 2) {
            int s = (i == 0) ? node : (int)csr[i - 1];
            ushort4v v = *(const ushort4v*)&hs[(size_t)s * 128 + colb];
#pragma unroll
            for (int j = 0; j < 4; ++j) acc[j] += h2f(v[j]);
        }
#pragma unroll
        for (int j = 0; j < 4; ++j) acc[j] += __shfl_xor(acc[j], 32);
        const float* bias = (b == 0 ? b2a : b == 1 ? b2b : b2c);
        const float di = dinv3[g];
#pragma unroll
        for (int j = 0; j < 4; ++j) f[b][j] = di * acc[j] + bias[l32 * 4 + j];
    }

    float4 w = *(const float4*)&attn_w[l32 * 4];
    float s0 = f[0][0] * w.x + f[0][1] * w.y + f[0][2] * w.z + f[0][3] * w.w;
    float s1 = f[1][0] * w.x + f[1][1] * w.y + f[1][2] * w.z + f[1][3] * w.w;
    float s2 = f[2][0] * w.x + f[2][1] * w.y + f[2][2] * w.z + f[2][3] * w.w;
#pragma unroll
    for (int m = 16; m >= 1; m >>= 1) {
        s0 += __shfl_xor(s0, m);
        s1 += __shfl_xor(s1, m);
        s2 += __shfl_xor(s2, m);
    }
    float bb = attn_b[0];
    s0 += bb; s1 += bb; s2 += bb;
    float mx = fmaxf(s0, fmaxf(s1, s2));
    float e0 = expf(s0 - mx), e1 = expf(s1 - mx), e2 = expf(s2 - mx);
    float inv = 1.f / (e0 + e1 + e2);
    e0 *= inv; e1 *= inv; e2 *= inv;

    if (half == 0) {
        float4 o;
        o.x = f[0][0] * e0 + f[1][0] * e1 + f[2][0] * e2;
        o.y = f[0][1] * e0 + f[1][1] * e1 + f[2][1] * e2;
        o.z = f[0][2] * e0 + f[1][2] * e1 + f[2][2] * e2;
        o.w = f[0][3] * e0 + f[1][3] * e1 + f[2][3] * e2;
        *(float4*)&out[(size_t)node * 128 + colb] = o;
    }
}

// ---------------- launch ----------------

extern "C" void kernel_launch(void* const* d_in, const int* in_sizes, int n_in,
                              void* d_out, int out_size, void* d_ws, size_t ws_size,
                              hipStream_t stream) {
    const float* x = (const float*)d_in[0];
    const int* e0 = (const int*)d_in[1];
    const int* e1 = (const int*)d_in[2];
    const int* e2 = (const int*)d_in[3];
    const float* attn_w = (const float*)d_in[16];
    const float* attn_b = (const float*)d_in[17];

    char* ws = (char*)d_ws;
    size_t off = 0;
    auto alloc = [&](size_t bytes) -> void* {
        void* p = ws + off;
        off += (bytes + 255) & ~(size_t)255;
        return p;
    };

    int* g_cur      = (int*)alloc(3 * BINS * 4);                    // zeroed
    int* seg3       = (int*)alloc((size_t)3 * NN * 4);
    int* cnt3       = (int*)alloc((size_t)3 * NN * 4);
    float* dinv3    = (float*)alloc((size_t)3 * NN * 4);
    ushort* g_csr   = (ushort*)alloc((size_t)3 * BINS * CAP * 2);   // 7.2 MB
    unsigned* g_bins = (unsigned*)alloc((size_t)3 * BINS * CAP * 4); // 14.5 MB
    ushort* x16     = (ushort*)alloc((size_t)NN * 256 * 2);         // 25.6 MB
    ushort* hs16all = (ushort*)alloc((size_t)3 * NN * 256 * 2);     // 76.8 MB
    ushort* hs2all  = (ushort*)alloc((size_t)3 * NN * 128 * 2);     // 38.4 MB
    ushort* BT1all  = (ushort*)alloc((size_t)3 * 256 * 256 * 2);
    ushort* BT2all  = (ushort*)alloc((size_t)3 * 128 * 256 * 2);

    hipMemsetAsync(g_cur, 0, 3 * BINS * 4, stream);

    // dispatch 1: edge binning | x->fp16 | W1^T | W2^T
    k_setup<<<BINB + WB + 768 + 384, 256, 0, stream>>>(
        e0, e1, e2, g_cur, g_bins, x, x16,
        (const float*)d_in[4], (const float*)d_in[8], (const float*)d_in[12], BT1all,
        (const float*)d_in[6], (const float*)d_in[10], (const float*)d_in[14], BT2all);

    // dispatch 2: CSR build (294 blocks) co-scheduled with GEMM1 (1176 blocks)
    k_build_gemm1<<<3 * BINS + 1176, 512, 0, stream>>>(
        g_bins, g_cur, g_csr, seg3, cnt3, dinv3, x16, BT1all, hs16all);

    // dispatch 3: fused layer-1 aggregation (h1 in LDS) + GEMM2 -> hs2
    k_agg1g2<<<3 * ((NN + 63) / 64), 256, 0, stream>>>(
        hs16all, seg3, cnt3, g_csr, dinv3,
        (const float*)d_in[5], (const float*)d_in[9], (const float*)d_in[13],
        BT2all, hs2all);

    // dispatch 4: fused layer-2 aggregation + attention
    k_final<<<WB, 256, 0, stream>>>(hs2all, seg3, cnt3, g_csr, dinv3,
                                    (const float*)d_in[7], (const float*)d_in[11],
                                    (const float*)d_in[15], attn_w, attn_b,
                                    (float*)d_out);
}

// Round 17
// 402.394 us; speedup vs baseline: 1.1988x; 1.1988x over previous
//
#include <hip/hip_runtime.h>

#define NN 50000
#define NE 800000
#define BINS 98      // bins of 512 nodes per branch
#define CAP 12288    // per-bin capacity (u32 records / ushort csr entries)
#define EPB 4096     // edges per phase-1 block
#define P1B ((NE + EPB - 1) / EPB)  // 196 blocks per branch
#define BINB (3 * P1B)              // 588 bin blocks
#define WB ((NN + 3) / 4)           // 12500

typedef __attribute__((ext_vector_type(8))) short short8;
typedef __attribute__((ext_vector_type(4))) float f32x4;
typedef __attribute__((ext_vector_type(8))) unsigned short ushort8v;
typedef __attribute__((ext_vector_type(4))) unsigned short ushort4v;
typedef _Float16 half8 __attribute__((ext_vector_type(8)));

__device__ __forceinline__ ushort f2h(float f) {
    _Float16 h = (_Float16)f;
    return __builtin_bit_cast(ushort, h);
}
__device__ __forceinline__ float h2f(ushort u) {
    return (float)__builtin_bit_cast(_Float16, u);
}

__device__ __forceinline__ int wave_incl_scan(int v, int lane) {
#pragma unroll
    for (int d = 1; d < 64; d <<= 1) {
        int u = __shfl_up(v, d);
        if (lane >= d) v += u;
    }
    return v;
}

// ---------------- setup dispatch: {edge binning | conv x16 | conv W1 | conv W2} ----

__global__ __launch_bounds__(256) void k_setup(
    const int* __restrict__ e0, const int* __restrict__ e1,
    const int* __restrict__ e2, int* __restrict__ g_cur,
    unsigned* __restrict__ g_bins,
    const float* __restrict__ x, ushort* __restrict__ x16,
    const float* __restrict__ w1a, const float* __restrict__ w1b,
    const float* __restrict__ w1c, ushort* __restrict__ BT1all,
    const float* __restrict__ w2a, const float* __restrict__ w2b,
    const float* __restrict__ w2c, ushort* __restrict__ BT2all) {
    const int tid = threadIdx.x;

    if (blockIdx.x < BINB) {
        const int br = blockIdx.x / P1B;
        const int cb = blockIdx.x % P1B;
        const int* ep = (br == 0 ? e0 : br == 1 ? e1 : e2);
        const int e_base = cb * EPB;

        __shared__ int s_cnt[BINS];
        __shared__ int s_start[BINS];
        __shared__ int s_cur[BINS];
        __shared__ int s_gb[BINS];
        __shared__ unsigned s_stage[EPB];

        if (tid < BINS) s_cnt[tid] = 0;
        __syncthreads();

        int4 s4[4], d4[4];
        bool valid[4];
#pragma unroll
        for (int i = 0; i < 4; ++i) {
            int idx = e_base + i * 1024 + tid * 4;
            valid[i] = (idx < NE);
            if (valid[i]) {
                s4[i] = *(const int4*)&ep[idx];
                d4[i] = *(const int4*)&ep[NE + idx];
                atomicAdd(&s_cnt[d4[i].x >> 9], 1);
                atomicAdd(&s_cnt[d4[i].y >> 9], 1);
                atomicAdd(&s_cnt[d4[i].z >> 9], 1);
                atomicAdd(&s_cnt[d4[i].w >> 9], 1);
            }
        }
        __syncthreads();
        if (tid == 0) {
            int run = 0;
            for (int b = 0; b < BINS; ++b) {
                s_start[b] = run;
                run += s_cnt[b];
            }
        }
        __syncthreads();
        if (tid < BINS) {
            s_cur[tid] = s_start[tid];
            int c = s_cnt[tid];
            int pc = (c + 15) & ~15;
            s_gb[tid] = (c > 0) ? atomicAdd(&g_cur[br * BINS + tid], pc) : 0;
        }
        __syncthreads();

#pragma unroll
        for (int i = 0; i < 4; ++i) {
            if (valid[i]) {
                int ss[4] = {s4[i].x, s4[i].y, s4[i].z, s4[i].w};
                int dd[4] = {d4[i].x, d4[i].y, d4[i].z, d4[i].w};
#pragma unroll
                for (int q = 0; q < 4; ++q) {
                    int bin = dd[q] >> 9;
                    int pos = atomicAdd(&s_cur[bin], 1);
                    s_stage[pos] = ((unsigned)(dd[q] & 511) << 16) | (unsigned)ss[q];
                }
            }
        }
        __syncthreads();

        for (int b = 0; b < BINS; ++b) {
            int c = s_cnt[b];
            if (c == 0) continue;
            int st = s_start[b];
            int gb = s_gb[b];
            int pc = (c + 15) & ~15;
            if (gb + pc > CAP) pc = (gb < CAP) ? (CAP - gb) : 0;
            size_t obase = (size_t)(br * BINS + b) * CAP + gb;
            for (int j = tid; j < pc; j += 256)
                g_bins[obase + j] = (j < c) ? s_stage[st + j] : 0x80000000u;
        }
        return;
    }

    int bb = blockIdx.x - BINB;
    if (bb < WB) {
        const int wid = tid >> 6, lane = tid & 63;
        const int row = bb * 4 + wid;
        if (row >= NN) return;
        float4 v = *(const float4*)&x[(size_t)row * 256 + lane * 4];
        ushort4 o;
        o.x = f2h(v.x); o.y = f2h(v.y); o.z = f2h(v.z); o.w = f2h(v.w);
        *(ushort4*)&x16[(size_t)row * 256 + lane * 4] = o;
        return;
    }
    bb -= WB;
    if (bb < 768) {
        int idx = bb * 256 + tid;  // 3 * 65536
        int b = idx >> 16, r = idx & 65535;
        int k = r >> 8, n = r & 255;
        const float* W = (b == 0 ? w1a : b == 1 ? w1b : w1c);
        BT1all[(size_t)b * 65536 + (size_t)n * 256 + k] = f2h(W[r]);
        return;
    }
    bb -= 768;
    {
        int idx = bb * 256 + tid;  // 3 * 32768
        int b = idx >> 15, r = idx & 32767;
        int k = r >> 7, n = r & 127;
        const float* W = (b == 0 ? w2a : b == 1 ? w2b : w2c);
        BT2all[(size_t)b * 32768 + (size_t)n * 256 + k] = f2h(W[r]);
    }
}

// ---------------- combined dispatch: {CSR build (294 blocks) | GEMM1 (1176)} ----

#define BGB 391  // gemm1 M-tiles per branch

__global__ __launch_bounds__(512) void k_build_gemm1(
    const unsigned* __restrict__ g_bins, const int* __restrict__ g_cur,
    ushort* __restrict__ g_csr, int* __restrict__ seg3, int* __restrict__ cnt3,
    float* __restrict__ dinv3,
    const ushort* __restrict__ x16, const ushort* __restrict__ BT1all,
    ushort* __restrict__ hs16all) {
    __shared__ ushort sA[2][128 * 32];
    __shared__ ushort sB[2][256 * 32];
    __shared__ int s_cnt[512];
    __shared__ int s_wsum[8];

    const int t = threadIdx.x, lane = t & 63, wid = t >> 6;

    if (blockIdx.x < 3 * BINS) {
        const int bid = blockIdx.x;
        const int br = bid / BINS;
        const int b2 = bid % BINS;
        const size_t base = (size_t)bid * CAP;
        const int node0 = b2 << 9;

        s_cnt[t] = 0;
        __syncthreads();

        const int total = min(g_cur[bid], CAP);
        for (int j = t; j < total; j += 512) {
            unsigned p = g_bins[base + j];
            if (!(p & 0x80000000u)) atomicAdd(&s_cnt[(p >> 16) & 0x1FF], 1);
        }
        __syncthreads();

        int c = s_cnt[t];
        int incl = wave_incl_scan(c, lane);
        if (lane == 63) s_wsum[wid] = incl;
        __syncthreads();
        int wpre = 0;
        for (int i = 0; i < wid; ++i) wpre += s_wsum[i];
        int ex = wpre + incl - c;

        int node = node0 + t;
        if (node < NN) {
            int g = br * NN + node;
            seg3[g] = (int)base + ex;
            cnt3[g] = c;
            dinv3[g] = rsqrtf((float)(c + 1));
        }
        __syncthreads();
        s_cnt[t] = ex;  // cursor
        __syncthreads();

        for (int j = t; j < total; j += 512) {
            unsigned p = g_bins[base + j];
            if (!(p & 0x80000000u)) {
                int loc = (p >> 16) & 0x1FF;
                int pos = atomicAdd(&s_cnt[loc], 1);
                g_csr[base + pos] = (ushort)(p & 0xFFFFu);
            }
        }
        return;
    }

    // ---------------- GEMM1 (512 threads, BM=128, BN=256, K=256) ----------
    constexpr int BM = 128, N = 256, KK = 256, BK = 32;
    constexpr int NW = 8, WGN = 4, NSTEP = KK / BK;
    const int sbid = blockIdx.x - 3 * BINS;
    int q = sbid >> 3, r = sbid & 7;
    int bid = (q / 3) * 8 + r;  // M-tile
    int kb = q % 3;             // branch
    if (bid >= BGB) return;

    const ushort* BT = BT1all + (size_t)kb * 65536;
    ushort* C = hs16all + (size_t)kb * NN * 256;
    const int wm = (wid / WGN) * 64, wn = (wid % WGN) * 64;
    const int bm = bid * BM;

    f32x4 zero = {0.f, 0.f, 0.f, 0.f};
    f32x4 acc[4][4];
#pragma unroll
    for (int m = 0; m < 4; ++m)
#pragma unroll
        for (int n = 0; n < 4; ++n) acc[m][n] = zero;

    auto stage = [&](int buf, int kt) {
        {
            int off = wid << 10;  // A: 1 issue
            int la = off + lane * 16;
            int row = la >> 6;
            int slot = (la >> 4) & 3;
            int scol = (slot ^ (row & 3)) << 4;
            int grow = bm + row;
            if (grow > NN - 1) grow = NN - 1;
            const char* ga = (const char*)x16 + (size_t)grow * (KK * 2) + kt * 2 + scol;
            __builtin_amdgcn_global_load_lds(
                (__attribute__((address_space(1))) const void*)ga,
                (__attribute__((address_space(3))) void*)((char*)sA[buf] + off), 16, 0, 0);
        }
#pragma unroll
        for (int i = 0; i < 2; ++i) {  // B: 2 issues
            int off = (wid + i * NW) << 10;
            int la = off + lane * 16;
            int row = la >> 6;
            int slot = (la >> 4) & 3;
            int scol = (slot ^ (row & 3)) << 4;
            const char* ga = (const char*)BT + (size_t)row * (KK * 2) + kt * 2 + scol;
            __builtin_amdgcn_global_load_lds(
                (__attribute__((address_space(1))) const void*)ga,
                (__attribute__((address_space(3))) void*)((char*)sB[buf] + off), 16, 0, 0);
        }
    };

    stage(0, 0);
    __syncthreads();

    int cur = 0;
    for (int ts = 0; ts < NSTEP; ++ts) {
        if (ts + 1 < NSTEP) stage(cur ^ 1, (ts + 1) * BK);

        const int s = lane >> 4;
        const int r0 = lane & 15;
        short8 af[4], bf[4];
#pragma unroll
        for (int m = 0; m < 4; ++m) {
            int row = wm + m * 16 + r0;
            af[m] = *(const short8*)((const char*)sA[cur] + row * 64 + ((s ^ (row & 3)) << 4));
        }
#pragma unroll
        for (int n = 0; n < 4; ++n) {
            int row = wn + n * 16 + r0;
            bf[n] = *(const short8*)((const char*)sB[cur] + row * 64 + ((s ^ (row & 3)) << 4));
        }
#pragma unroll
        for (int m = 0; m < 4; ++m)
#pragma unroll
            for (int n = 0; n < 4; ++n)
                acc[m][n] = __builtin_amdgcn_mfma_f32_16x16x32_f16(
                    __builtin_bit_cast(half8, af[m]), __builtin_bit_cast(half8, bf[n]),
                    acc[m][n], 0, 0, 0);
        __syncthreads();
        cur ^= 1;
    }

    const int cr0 = (lane >> 4) * 4;
    const int cc = lane & 15;
#pragma unroll
    for (int m = 0; m < 4; ++m) {
#pragma unroll
        for (int rg = 0; rg < 4; ++rg) {
            int row = bm + wm + m * 16 + cr0 + rg;
            if (row < NN) {
#pragma unroll
                for (int n = 0; n < 4; ++n)
                    C[(size_t)row * N + wn + n * 16 + cc] = f2h(acc[m][n][rg]);
            }
        }
    }
}

// ---------------- GEMM2: hs2 = dinv * (h1 @ W2), fp16 K=256 ----------------

__global__ __launch_bounds__(256) void k_gemm2(
    const ushort* __restrict__ h1all, const ushort* __restrict__ BT2all,
    const float* __restrict__ dinv3, ushort* __restrict__ hs2all) {
    constexpr int BM = 128, BN = 128, N = 128, KK = 256, BK = 32;
    constexpr int NW = 4, WGN = 2, NSTEP = KK / BK;
    constexpr int MT = (NN + BM - 1) / BM;
    __shared__ ushort sA[2][BM * 32];
    __shared__ ushort sB[2][BN * 32];
    const int kb = blockIdx.x / MT;
    const int bid = blockIdx.x % MT;
    const ushort* Ab = h1all + (size_t)kb * NN * 256;
    const ushort* BT = BT2all + (size_t)kb * 32768;
    const float* dinv = dinv3 + (size_t)kb * NN;
    ushort* C = hs2all + (size_t)kb * NN * 128;
    const int t = threadIdx.x, lane = t & 63, wid = t >> 6;
    const int wm = (wid / WGN) * 64, wn = (wid % WGN) * 64;
    const int bm = bid * BM;

    f32x4 zero = {0.f, 0.f, 0.f, 0.f};
    f32x4 acc[4][4];
#pragma unroll
    for (int m = 0; m < 4; ++m)
#pragma unroll
        for (int n = 0; n < 4; ++n) acc[m][n] = zero;

    auto stage = [&](int buf, int kt) {
#pragma unroll
        for (int i = 0; i < 2; ++i) {  // A: 2 issues
            int off = (wid + i * NW) << 10;
            int la = off + lane * 16;
            int row = la >> 6;
            int slot = (la >> 4) & 3;
            int scol = (slot ^ (row & 3)) << 4;
            int grow = bm + row;
            if (grow > NN - 1) grow = NN - 1;
            const char* ga = (const char*)Ab + (size_t)grow * (KK * 2) + kt * 2 + scol;
            __builtin_amdgcn_global_load_lds(
                (__attribute__((address_space(1))) const void*)ga,
                (__attribute__((address_space(3))) void*)((char*)sA[buf] + off), 16, 0, 0);
        }
#pragma unroll
        for (int i = 0; i < 2; ++i) {  // B: 2 issues
            int off = (wid + i * NW) << 10;
            int la = off + lane * 16;
            int row = la >> 6;
            int slot = (la >> 4) & 3;
            int scol = (slot ^ (row & 3)) << 4;
            const char* ga = (const char*)BT + (size_t)row * (KK * 2) + kt * 2 + scol;
            __builtin_amdgcn_global_load_lds(
                (__attribute__((address_space(1))) const void*)ga,
                (__attribute__((address_space(3))) void*)((char*)sB[buf] + off), 16, 0, 0);
        }
    };

    stage(0, 0);
    __syncthreads();

    int cur = 0;
    for (int ts = 0; ts < NSTEP; ++ts) {
        if (ts + 1 < NSTEP) stage(cur ^ 1, (ts + 1) * BK);

        const int s = lane >> 4;
        const int r0 = lane & 15;
        short8 af[4], bf[4];
#pragma unroll
        for (int m = 0; m < 4; ++m) {
            int row = wm + m * 16 + r0;
            af[m] = *(const short8*)((const char*)sA[cur] + row * 64 + ((s ^ (row & 3)) << 4));
        }
#pragma unroll
        for (int n = 0; n < 4; ++n) {
            int row = wn + n * 16 + r0;
            bf[n] = *(const short8*)((const char*)sB[cur] + row * 64 + ((s ^ (row & 3)) << 4));
        }
#pragma unroll
        for (int m = 0; m < 4; ++m)
#pragma unroll
            for (int n = 0; n < 4; ++n)
                acc[m][n] = __builtin_amdgcn_mfma_f32_16x16x32_f16(
                    __builtin_bit_cast(half8, af[m]), __builtin_bit_cast(half8, bf[n]),
                    acc[m][n], 0, 0, 0);
        __syncthreads();
        cur ^= 1;
    }

    const int cr0 = (lane >> 4) * 4;
    const int cc = lane & 15;
#pragma unroll
    for (int m = 0; m < 4; ++m) {
#pragma unroll
        for (int rg = 0; rg < 4; ++rg) {
            int row = bm + wm + m * 16 + cr0 + rg;
            if (row < NN) {
                float dv = dinv[row];
#pragma unroll
                for (int n = 0; n < 4; ++n)
                    C[(size_t)row * N + wn + n * 16 + cc] = f2h(acc[m][n][rg] * dv);
            }
        }
    }
}

// ---------------- layer-1 aggregation (per-neighbor dinv weights) ----------

#define UTOT (3 * 12500)

__global__ __launch_bounds__(256) void k_agg1(const ushort* __restrict__ hs16all,
                                              const int* __restrict__ seg3,
                                              const int* __restrict__ cnt3,
                                              const ushort* __restrict__ g_csr,
                                              const float* __restrict__ dinv3,
                                              const float* __restrict__ b1a,
                                              const float* __restrict__ b1b,
                                              const float* __restrict__ b1c,
                                              ushort* __restrict__ h1all) {
    const int x = blockIdx.x & 7, j = blockIdx.x >> 3;
    const int start = (x * UTOT) >> 3;
    const int end = ((x + 1) * UTOT) >> 3;
    const int u = start + j;
    if (u >= end) return;
    const int b = u / 12500;
    const int blk = u % 12500;

    const int wid = threadIdx.x >> 6;
    const int lane = threadIdx.x & 63;
    const int node = blk * 4 + wid;
    if (node >= NN) return;
    const int half = lane >> 5, l32 = lane & 31;
    const int g = b * NN + node;
    const ushort* hs = hs16all + (size_t)b * NN * 256;
    const float* dv = dinv3 + (size_t)b * NN;
    const ushort* csr = g_csr + seg3[g];
    const int len = cnt3[g] + 1;
    const size_t colb = (size_t)l32 * 8;

    float acc[8] = {0.f, 0.f, 0.f, 0.f, 0.f, 0.f, 0.f, 0.f};
    int i = half;
    for (; i + 6 < len; i += 8) {
        int s0 = (i == 0) ? node : (int)csr[i - 1];
        int s1 = (int)csr[i + 1];
        int s2 = (int)csr[i + 3];
        int s3 = (int)csr[i + 5];
        float d0 = dv[s0], d1 = dv[s1], d2 = dv[s2], d3 = dv[s3];
        ushort8v v0 = *(const ushort8v*)&hs[(size_t)s0 * 256 + colb];
        ushort8v v1 = *(const ushort8v*)&hs[(size_t)s1 * 256 + colb];
        ushort8v v2 = *(const ushort8v*)&hs[(size_t)s2 * 256 + colb];
        ushort8v v3 = *(const ushort8v*)&hs[(size_t)s3 * 256 + colb];
#pragma unroll
        for (int jq = 0; jq < 8; ++jq)
            acc[jq] += (d0 * h2f(v0[jq]) + d1 * h2f(v1[jq])) +
                       (d2 * h2f(v2[jq]) + d3 * h2f(v3[jq]));
    }
    for (; i < len; i += 2) {
        int s = (i == 0) ? node : (int)csr[i - 1];
        float d = dv[s];
        ushort8v v = *(const ushort8v*)&hs[(size_t)s * 256 + colb];
#pragma unroll
        for (int jq = 0; jq < 8; ++jq) acc[jq] += d * h2f(v[jq]);
    }
#pragma unroll
    for (int jq = 0; jq < 8; ++jq) acc[jq] += __shfl_xor(acc[jq], 32);

    if (half == 0) {
        const float* bias = (b == 0 ? b1a : b == 1 ? b1b : b1c);
        const float di = dv[node];
        ushort8v o;
#pragma unroll
        for (int jq = 0; jq < 8; ++jq) {
            float r = fmaxf(di * acc[jq] + bias[l32 * 8 + jq], 0.f);
            o[jq] = f2h(r);
        }
        *(ushort8v*)&h1all[((size_t)b * NN + node) * 256 + colb] = o;
    }
}

// ---------------- fused layer-2 aggregation (x3) + attention ----------------

__global__ __launch_bounds__(256) void k_final(const ushort* __restrict__ hs2all,
                                               const int* __restrict__ seg3,
                                               const int* __restrict__ cnt3,
                                               const ushort* __restrict__ g_csr,
                                               const float* __restrict__ dinv3,
                                               const float* __restrict__ b2a,
                                               const float* __restrict__ b2b,
                                               const float* __restrict__ b2c,
                                               const float* __restrict__ attn_w,
                                               const float* __restrict__ attn_b,
                                               float* __restrict__ out) {
    const int wid = threadIdx.x >> 6;
    const int lane = threadIdx.x & 63;
    const int node = blockIdx.x * 4 + wid;
    if (node >= NN) return;
    const int half = lane >> 5, l32 = lane & 31;
    const size_t colb = (size_t)l32 * 4;

    float f[3][4];
#pragma unroll
    for (int b = 0; b < 3; ++b) {
        const int g = b * NN + node;
        const ushort* hs = hs2all + (size_t)b * NN * 128;
        const ushort* csr = g_csr + seg3[g];
        const int len = cnt3[g] + 1;
        float acc[4] = {0.f, 0.f, 0.f, 0.f};
        int i = half;
        for (; i + 6 < len; i += 8) {
            int s0 = (i == 0) ? node : (int)csr[i - 1];
            int s1 = (int)csr[i + 1];
            int s2 = (int)csr[i + 3];
            int s3 = (int)csr[i + 5];
            ushort4v v0 = *(const ushort4v*)&hs[(size_t)s0 * 128 + colb];
            ushort4v v1 = *(const ushort4v*)&hs[(size_t)s1 * 128 + colb];
            ushort4v v2 = *(const ushort4v*)&hs[(size_t)s2 * 128 + colb];
            ushort4v v3 = *(const ushort4v*)&hs[(size_t)s3 * 128 + colb];
#pragma unroll
            for (int j = 0; j < 4; ++j)
                acc[j] += (h2f(v0[j]) + h2f(v1[j])) + (h2f(v2[j]) + h2f(v3[j]));
        }
        for (; i < len; i += 2) {
            int s = (i == 0) ? node : (int)csr[i - 1];
            ushort4v v = *(const ushort4v*)&hs[(size_t)s * 128 + colb];
#pragma unroll
            for (int j = 0; j < 4; ++j) acc[j] += h2f(v[j]);
        }
#pragma unroll
        for (int j = 0; j < 4; ++j) acc[j] += __shfl_xor(acc[j], 32);
        const float* bias = (b == 0 ? b2a : b == 1 ? b2b : b2c);
        const float di = dinv3[g];
#pragma unroll
        for (int j = 0; j < 4; ++j) f[b][j] = di * acc[j] + bias[l32 * 4 + j];
    }

    float4 w = *(const float4*)&attn_w[l32 * 4];
    float s0 = f[0][0] * w.x + f[0][1] * w.y + f[0][2] * w.z + f[0][3] * w.w;
    float s1 = f[1][0] * w.x + f[1][1] * w.y + f[1][2] * w.z + f[1][3] * w.w;
    float s2 = f[2][0] * w.x + f[2][1] * w.y + f[2][2] * w.z + f[2][3] * w.w;
#pragma unroll
    for (int m = 16; m >= 1; m >>= 1) {
        s0 += __shfl_xor(s0, m);
        s1 += __shfl_xor(s1, m);
        s2 += __shfl_xor(s2, m);
    }
    float bb = attn_b[0];
    s0 += bb; s1 += bb; s2 += bb;
    float mx = fmaxf(s0, fmaxf(s1, s2));
    float e0 = expf(s0 - mx), e1 = expf(s1 - mx), e2 = expf(s2 - mx);
    float inv = 1.f / (e0 + e1 + e2);
    e0 *= inv; e1 *= inv; e2 *= inv;

    if (half == 0) {
        float4 o;
        o.x = f[0][0] * e0 + f[1][0] * e1 + f[2][0] * e2;
        o.y = f[0][1] * e0 + f[1][1] * e1 + f[2][1] * e2;
        o.z = f[0][2] * e0 + f[1][2] * e1 + f[2][2] * e2;
        o.w = f[0][3] * e0 + f[1][3] * e1 + f[2][3] * e2;
        *(float4*)&out[(size_t)node * 128 + colb] = o;
    }
}

// ---------------- launch ----------------

extern "C" void kernel_launch(void* const* d_in, const int* in_sizes, int n_in,
                              void* d_out, int out_size, void* d_ws, size_t ws_size,
                              hipStream_t stream) {
    const float* x = (const float*)d_in[0];
    const int* e0 = (const int*)d_in[1];
    const int* e1 = (const int*)d_in[2];
    const int* e2 = (const int*)d_in[3];
    const float* attn_w = (const float*)d_in[16];
    const float* attn_b = (const float*)d_in[17];

    char* ws = (char*)d_ws;
    size_t off = 0;
    auto alloc = [&](size_t bytes) -> void* {
        void* p = ws + off;
        off += (bytes + 255) & ~(size_t)255;
        return p;
    };

    int* g_cur      = (int*)alloc(3 * BINS * 4);                    // zeroed
    int* seg3       = (int*)alloc((size_t)3 * NN * 4);
    int* cnt3       = (int*)alloc((size_t)3 * NN * 4);
    float* dinv3    = (float*)alloc((size_t)3 * NN * 4);
    ushort* g_csr   = (ushort*)alloc((size_t)3 * BINS * CAP * 2);   // 7.2 MB
    ushort* x16     = (ushort*)alloc((size_t)NN * 256 * 2);         // 25.6 MB
    ushort* hs16all = (ushort*)alloc((size_t)3 * NN * 256 * 2);     // 76.8 MB
    ushort* h1all   = (ushort*)alloc((size_t)3 * NN * 256 * 2);     // 76.8 MB
    unsigned* g_bins = (unsigned*)h1all;  // alias: g_bins dead before h1all written
    ushort* hs2all  = (ushort*)alloc((size_t)3 * NN * 128 * 2);     // 38.4 MB
    ushort* BT1all  = (ushort*)alloc((size_t)3 * 256 * 256 * 2);
    ushort* BT2all  = (ushort*)alloc((size_t)3 * 128 * 256 * 2);

    hipMemsetAsync(g_cur, 0, 3 * BINS * 4, stream);

    // dispatch 1: edge binning | x->fp16 | W1^T | W2^T
    k_setup<<<BINB + WB + 768 + 384, 256, 0, stream>>>(
        e0, e1, e2, g_cur, g_bins, x, x16,
        (const float*)d_in[4], (const float*)d_in[8], (const float*)d_in[12], BT1all,
        (const float*)d_in[6], (const float*)d_in[10], (const float*)d_in[14], BT2all);

    // dispatch 2: CSR build (294 blocks) co-scheduled with GEMM1 (1176 blocks)
    k_build_gemm1<<<3 * BINS + 1176, 512, 0, stream>>>(
        g_bins, g_cur, g_csr, seg3, cnt3, dinv3, x16, BT1all, hs16all);

    // dispatch 3: layer-1 aggregation (per-neighbor dinv) -> h1 fp16
    k_agg1<<<8 * ((UTOT + 7) / 8), 256, 0, stream>>>(
        hs16all, seg3, cnt3, g_csr, dinv3,
        (const float*)d_in[5], (const float*)d_in[9], (const float*)d_in[13], h1all);

    // dispatch 4: hs2 = dinv*(h1 @ W2)
    k_gemm2<<<3 * 391, 256, 0, stream>>>(h1all, BT2all, dinv3, hs2all);

    // dispatch 5: fused layer-2 aggregation + attention
    k_final<<<WB, 256, 0, stream>>>(hs2all, seg3, cnt3, g_csr, dinv3,
                                    (const float*)d_in[7], (const float*)d_in[11],
                                    (const float*)d_in[15], attn_w, attn_b,
                                    (float*)d_out);
}